// Round 4
// baseline (446.162 us; speedup 1.0000x reference)
//
#include <hip/hip_runtime.h>
#include <math.h>

#define HDIM 768
#define HIDD 512
#define NTOK 16384
#define NT 20
#define CHUNKS 128
#define CLEN 128

typedef unsigned short ushort_t;
typedef __attribute__((ext_vector_type(8))) short bf16x8;
typedef __attribute__((ext_vector_type(4))) float f32x4;

__device__ __forceinline__ float sigm(float x){ return 1.0f/(1.0f+expf(-x)); }

__device__ __forceinline__ ushort_t f2bf(float f){
    unsigned int u = __float_as_uint(f);
    unsigned int r = (u + 0x7fffu + ((u >> 16) & 1u)) >> 16;
    return (ushort_t)r;
}
__device__ __forceinline__ float bf2f(ushort_t b){
    return __uint_as_float(((unsigned int)b) << 16);
}

#define GLD16(gp, lp) __builtin_amdgcn_global_load_lds( \
    (const __attribute__((address_space(1))) void*)(gp), \
    (__attribute__((address_space(3))) void*)(lp), 16, 0, 0)

// ---------------------------------------------------------------------------
// Fused conversion kernel: blocks [0,1152) pack B (w_ih f/b gates i,g,o),
// blocks [1152, 13440) split x rows 1..16384 into bf16 hi/lo.
// ---------------------------------------------------------------------------
__global__ __launch_bounds__(256) void conv_kernel(
    const float* __restrict__ x,
    const float* __restrict__ wf, const float* __restrict__ wb,
    ushort_t* __restrict__ Ah, ushort_t* __restrict__ Al,
    ushort_t* __restrict__ Bh, ushort_t* __restrict__ Bl)
{
    const int bid = blockIdx.x;
    if (bid < 1152){
        int t = bid*256 + threadIdx.x;                 // 1536*192
        int n = t / 192, c4 = (t - n*192)*4;
        int dir = n / 768, nr = n - dir*768;
        int gate = nr >> 8, j = nr & 255;
        int wrow = j + ((gate==0)?0:((gate==1)?512:768));
        const float* src = dir ? wb : wf;
        const float4 v = *(const float4*)(src + (size_t)wrow*HDIM + c4);
        float f[4] = {v.x, v.y, v.z, v.w};
        ushort_t h[4], l[4];
        #pragma unroll
        for (int i=0;i<4;++i){
            h[i] = f2bf(f[i]);
            l[i] = f2bf(f[i] - bf2f(h[i]));
        }
        *(ushort4*)(Bh + (size_t)n*HDIM + c4) = make_ushort4(h[0],h[1],h[2],h[3]);
        *(ushort4*)(Bl + (size_t)n*HDIM + c4) = make_ushort4(l[0],l[1],l[2],l[3]);
    } else {
        int t = (bid-1152)*256 + threadIdx.x;          // 16384*192
        int row = t / 192, c4 = (t - row*192)*4;
        const float4 v = *(const float4*)(x + (size_t)(row+1)*HDIM + c4);
        float f[4] = {v.x, v.y, v.z, v.w};
        ushort_t h[4], l[4];
        #pragma unroll
        for (int i=0;i<4;++i){
            h[i] = f2bf(f[i]);
            l[i] = f2bf(f[i] - bf2f(h[i]));
        }
        *(ushort4*)(Ah + (size_t)row*HDIM + c4) = make_ushort4(h[0],h[1],h[2],h[3]);
        *(ushort4*)(Al + (size_t)row*HDIM + c4) = make_ushort4(l[0],l[1],l[2],l[3]);
    }
}

// ---------------------------------------------------------------------------
// Fused split-bf16 MFMA GEMM + gates + partial-feats epilogue.
// m-tile 64 x n-tile 128 (one dir, one j-half), BK=32, 3 gate passes.
// 32 KB LDS/block -> 4 blocks/CU (latency hiding via cross-block overlap).
// Block swizzle: all 4 q-blocks of an m-tile land on the same XCD (bx&7) so
// A-tiles are L2-served after one HBM fetch; B working set is L2-resident.
// K-chunk order identical to previous round -> bit-identical results.
// ---------------------------------------------------------------------------
__global__ __launch_bounds__(256, 4) void gemm_fused(
    const ushort_t* __restrict__ Ah, const ushort_t* __restrict__ Al,
    const ushort_t* __restrict__ Bh, const ushort_t* __restrict__ Bl,
    const float* __restrict__ bihf, const float* __restrict__ bhhf,
    const float* __restrict__ bihb, const float* __restrict__ bhhb,
    const float* __restrict__ wtag, float* __restrict__ featsp)
{
    __shared__ __align__(16) char smem[32768];
    ushort_t* As_h = (ushort_t*)smem;              // 64x32 bf16 swizzled, 4KB
    ushort_t* As_l = (ushort_t*)(smem + 4096);     // 4KB
    ushort_t* Bs_h = (ushort_t*)(smem + 8192);     // 128x32, 8KB
    ushort_t* Bs_l = (ushort_t*)(smem + 16384);    // 8KB
    float* hbuf = (float*)smem;                    // epilogue: 32x129 f32 (16512B)
    float* wts  = (float*)(smem + 16512);          // epilogue: 20x128 f32 (10240B)

    const int tid = threadIdx.x;
    const int bx = blockIdx.x;
    const int xcd = bx & 7, bidx = bx >> 3;
    const int q = bidx & 3, mt = (bidx >> 2)*8 + xcd;   // 4 q-blocks share XCD
    const int dir = q >> 1, j0 = (q & 1)*128;
    const int row0 = mt*64;
    const float* __restrict__ bih = dir ? bihb : bihf;
    const float* __restrict__ bhh = dir ? bhhb : bhhf;

    const int lane = tid & 63, wv = tid >> 6;
    const int wm = wv >> 1, wn = wv & 1;
    const int lm = lane & 15, lq = lane >> 4;
    const int wbase = (tid & 192) * 8;             // wave-uniform LDS ushort base

    // staging: thread tid owns lds slot tid (A) / g*256+tid (B); slot=(r,k8')
    const int sr = tid >> 2;
    const int k8s = (tid & 3) ^ ((sr & 3) ^ ((sr >> 2) & 3));
    const size_t aoffe = (size_t)(row0 + sr)*HDIM + k8s*8;
    size_t boffe[2];
    #pragma unroll
    for (int g=0; g<2; ++g)
        boffe[g] = (size_t)(g*64 + sr)*HDIM + k8s*8;   // + nbase*HDIM per pass

    // fragment ds_read offsets (ushort idx), swizzle-matched
    int aoff_lds[2], boff_lds[4];
    #pragma unroll
    for (int f=0; f<2; ++f){
        int m = wm*32 + f*16 + lm;
        int k8p = (lq ^ (m & 3) ^ ((m >> 2) & 3)) & 3;
        aoff_lds[f] = (m*4 + k8p)*8;
    }
    #pragma unroll
    for (int f=0; f<4; ++f){
        int n = wn*64 + f*16 + lm;
        int k8p = (lq ^ (n & 3) ^ ((n >> 2) & 3)) & 3;
        boff_lds[f] = (n*4 + k8p)*8;
    }

    int jcol[4];
    #pragma unroll
    for (int fn=0; fn<4; ++fn) jcol[fn] = j0 + wn*64 + fn*16 + lm;

    float held[2][4][4];
    f32x4 acc[2][4];

    #pragma unroll 1
    for (int p=0; p<3; ++p){
        const size_t bbase = (size_t)(dir*768 + p*256 + j0)*HDIM;

        #pragma unroll
        for (int fm=0; fm<2; ++fm)
            #pragma unroll
            for (int fn=0; fn<4; ++fn)
                acc[fm][fn] = (f32x4){0.f,0.f,0.f,0.f};

        #pragma unroll 1
        for (int kt=0; kt<24; ++kt){
            const int k0 = kt*32;
            GLD16(Ah + aoffe + k0,            &As_h[wbase]);
            GLD16(Al + aoffe + k0,            &As_l[wbase]);
            GLD16(Bh + bbase + boffe[0] + k0, &Bs_h[wbase]);
            GLD16(Bh + bbase + boffe[1] + k0, &Bs_h[2048 + wbase]);
            GLD16(Bl + bbase + boffe[0] + k0, &Bs_l[wbase]);
            GLD16(Bl + bbase + boffe[1] + k0, &Bs_l[2048 + wbase]);
            __syncthreads();
            bf16x8 afh[2], afl[2], bfh[4], bfl[4];
            #pragma unroll
            for (int f=0; f<2; ++f){
                afh[f] = *(const bf16x8*)&As_h[aoff_lds[f]];
                afl[f] = *(const bf16x8*)&As_l[aoff_lds[f]];
            }
            #pragma unroll
            for (int f=0; f<4; ++f){
                bfh[f] = *(const bf16x8*)&Bs_h[boff_lds[f]];
                bfl[f] = *(const bf16x8*)&Bs_l[boff_lds[f]];
            }
            #pragma unroll
            for (int fm=0; fm<2; ++fm)
                #pragma unroll
                for (int fn=0; fn<4; ++fn){
                    acc[fm][fn] = __builtin_amdgcn_mfma_f32_16x16x32_bf16(
                        afh[fm], bfh[fn], acc[fm][fn], 0, 0, 0);
                    acc[fm][fn] = __builtin_amdgcn_mfma_f32_16x16x32_bf16(
                        afl[fm], bfh[fn], acc[fm][fn], 0, 0, 0);
                    acc[fm][fn] = __builtin_amdgcn_mfma_f32_16x16x32_bf16(
                        afh[fm], bfl[fn], acc[fm][fn], 0, 0, 0);
                }
            __syncthreads();
        }

        const int gbase = (p==0) ? 0 : ((p==1) ? 512 : 768);
        float bias[4];
        #pragma unroll
        for (int fn=0; fn<4; ++fn)
            bias[fn] = bih[gbase + jcol[fn]] + bhh[gbase + jcol[fn]];

        if (p==0){
            #pragma unroll
            for (int fm=0; fm<2; ++fm)
                #pragma unroll
                for (int fn=0; fn<4; ++fn)
                    #pragma unroll
                    for (int r=0; r<4; ++r)
                        held[fm][fn][r] = sigm(acc[fm][fn][r] + bias[fn]);
        } else if (p==1){
            #pragma unroll
            for (int fm=0; fm<2; ++fm)
                #pragma unroll
                for (int fn=0; fn<4; ++fn)
                    #pragma unroll
                    for (int r=0; r<4; ++r)
                        held[fm][fn][r] *= tanhf(acc[fm][fn][r] + bias[fn]);
        } else {
            float hv[2][4][4];
            #pragma unroll
            for (int fm=0; fm<2; ++fm)
                #pragma unroll
                for (int fn=0; fn<4; ++fn)
                    #pragma unroll
                    for (int r=0; r<4; ++r)
                        hv[fm][fn][r] = sigm(acc[fm][fn][r] + bias[fn]) * tanhf(held[fm][fn][r]);

            // wtag slice (last K-loop iter ended with __syncthreads; tiles dead)
            for (int i2=tid; i2<NT*128; i2+=256){
                int t = i2 >> 7, j = i2 & 127;
                wts[i2] = wtag[t*HIDD + dir*256 + j0 + j];
            }
            float* fq = featsp + (size_t)q * (NTOK*NT);
            #pragma unroll 1
            for (int ph=0; ph<2; ++ph){
                __syncthreads();
                if (wm == ph){
                    #pragma unroll
                    for (int fm=0; fm<2; ++fm)
                        #pragma unroll
                        for (int fn=0; fn<4; ++fn)
                            #pragma unroll
                            for (int r=0; r<4; ++r){
                                int mloc = fm*16 + lq*4 + r;         // 0..31
                                int jloc = wn*64 + fn*16 + lm;       // 0..127
                                hbuf[mloc*129 + jloc] = hv[fm][fn][r];
                            }
                }
                __syncthreads();
                const int mrow = tid & 31, grp = tid >> 5;           // 8 groups
                if (grp < 5){
                    const int tg0 = grp*4;
                    float s[4] = {0.f,0.f,0.f,0.f};
                    for (int j=0;j<128;++j){
                        float h = hbuf[mrow*129 + j];
                        #pragma unroll
                        for (int tt=0; tt<4; ++tt)
                            s[tt] = fmaf(h, wts[(tg0+tt)*128 + j], s[tt]);
                    }
                    const int mglob = row0 + ph*32 + mrow;
                    #pragma unroll
                    for (int tt=0; tt<4; ++tt)
                        fq[(size_t)mglob*NT + tg0 + tt] = s[tt];
                }
            }
        }
    }
}

// ---------------------------------------------------------------------------
// fl loader shared by chunkmat/replay: identical deterministic sum of the 4
// partial buffers + btag (bit-identical across both kernels).
// ---------------------------------------------------------------------------
__device__ __forceinline__ void load_fl(
    const float* __restrict__ featsp, const float* __restrict__ btg,
    float* fl, int c, int tid, int nthr)
{
    const float4* p0 = (const float4*)(featsp);
    const float4* p1 = (const float4*)(featsp + (size_t)NTOK*NT);
    const float4* p2 = (const float4*)(featsp + (size_t)2*NTOK*NT);
    const float4* p3 = (const float4*)(featsp + (size_t)3*NTOK*NT);
    const int base = c*(CLEN*NT/4);
    for (int idx=tid; idx<CLEN*NT/4; idx+=nthr){
        float4 a = p0[base+idx], b = p1[base+idx];
        float4 d = p2[base+idx], e = p3[base+idx];
        float4 v;
        v.x = (a.x+b.x)+(d.x+e.x);
        v.y = (a.y+b.y)+(d.y+e.y);
        v.z = (a.z+b.z)+(d.z+e.z);
        v.w = (a.w+b.w)+(d.w+e.w);
        int t0 = (idx*4) % 20;
        v.x += btg[t0]; v.y += btg[t0+1]; v.z += btg[t0+2]; v.w += btg[t0+3];
        ((float4*)fl)[idx] = v;
    }
}

// ---------------------------------------------------------------------------
// V1: per-chunk max-plus matrix product P_c (20x20). One block per chunk.
// ---------------------------------------------------------------------------
__global__ __launch_bounds__(512) void vit_chunkmat(
    const float* __restrict__ featsp, const float* __restrict__ btag,
    const float* __restrict__ trans, float* __restrict__ Pall)
{
    __shared__ float fl[CLEN*NT];
    __shared__ float Pb[2][NT*NT];
    const int c = blockIdx.x, tid = threadIdx.x;
    load_fl(featsp, btag, fl, c, tid, 512);
    const bool act = tid < NT*NT;
    const int i = tid/20, j = tid - i*20;
    float tr[NT];
    if (act){
        #pragma unroll
        for (int k=0;k<NT;++k) tr[k] = trans[i*NT+k];
        Pb[0][tid] = (i==j) ? 0.f : -1e30f;
    }
    __syncthreads();
    int cur = 0;
    for (int t=0;t<CLEN;++t){
        float m = -3.0e38f;
        if (act){
            #pragma unroll
            for (int k=0;k<NT;++k) m = fmaxf(m, tr[k] + Pb[cur][k*NT+j]);
            m += fl[t*NT+i];
            Pb[cur^1][tid] = m;
        }
        __syncthreads();
        cur ^= 1;
    }
    if (act) Pall[(size_t)c*(NT*NT) + tid] = Pb[cur][tid];
}

// ---------------------------------------------------------------------------
// V2: sequential chunk scan -> fv at chunk starts + terminal argmax/score.
// ---------------------------------------------------------------------------
__global__ __launch_bounds__(128) void vit_scan(
    const float* __restrict__ Pall, const float* __restrict__ trans,
    float* __restrict__ fvstart, float* __restrict__ dout, int* __restrict__ bestws)
{
    __shared__ float Pb[NT*NT];
    __shared__ float fv[NT];
    const int tid = threadIdx.x;
    float4 pn = {0.f,0.f,0.f,0.f};
    if (tid<100) pn = ((const float4*)Pall)[tid];
    if (tid<NT) fv[tid] = (tid==18) ? 0.f : -10000.f;
    for (int c=0;c<CHUNKS;++c){
        if (tid<100) ((float4*)Pb)[tid] = pn;
        if (tid<100 && c+1<CHUNKS) pn = ((const float4*)(Pall + (size_t)(c+1)*(NT*NT)))[tid];
        __syncthreads();
        if (tid<NT) fvstart[c*NT+tid] = fv[tid];
        float nf = -3.0e38f;
        if (tid<NT){
            #pragma unroll
            for (int j=0;j<NT;++j) nf = fmaxf(nf, Pb[tid*NT+j] + fv[j]);
        }
        __syncthreads();
        if (tid<NT) fv[tid] = nf;
    }
    __syncthreads();
    if (tid==0){
        float best = -3.0e38f; int bidx = 0;
        for (int j=0;j<NT;++j){
            float tv = fv[j] + trans[19*NT+j];
            if (tv > best){ best = tv; bidx = j; }
        }
        dout[0] = best;
        bestws[0] = bidx;
    }
}

// ---------------------------------------------------------------------------
// V3: exact per-step replay (reference argmax semantics) -> backpointers + H_c
// ---------------------------------------------------------------------------
__global__ __launch_bounds__(64) void vit_replay(
    const float* __restrict__ featsp, const float* __restrict__ btag,
    const float* __restrict__ trans, const float* __restrict__ fvstart,
    unsigned int* __restrict__ bpout, int* __restrict__ Hout)
{
    __shared__ float fl[CLEN*NT];
    __shared__ float fv[NT];
    __shared__ unsigned char bp[CLEN*NT];
    const int c = blockIdx.x, tid = threadIdx.x;
    load_fl(featsp, btag, fl, c, tid, 64);
    float tr[NT];
    if (tid<NT){
        fv[tid] = fvstart[c*NT+tid];
        #pragma unroll
        for (int k=0;k<NT;++k) tr[k] = trans[tid*NT+k];
    }
    __syncthreads();
    for (int t=0;t<CLEN;++t){
        float best = 0.f; int bj = 0;
        if (tid<NT){
            best = tr[0] + fv[0];
            #pragma unroll
            for (int j=1;j<NT;++j){
                float v = tr[j] + fv[j];
                if (v > best){ best = v; bj = j; }
            }
        }
        __syncthreads();
        if (tid<NT){
            fv[tid] = best + fl[t*NT+tid];
            bp[t*NT+tid] = (unsigned char)bj;
        }
        __syncthreads();
    }
    for (int idx=tid; idx<CLEN*NT/4; idx+=64)
        bpout[(size_t)c*(CLEN*NT/4) + idx] = ((unsigned int*)bp)[idx];
    if (tid<NT){
        int m = tid;
        for (int t=CLEN-1;t>=0;--t) m = bp[t*NT+m];
        Hout[c*NT+tid] = m;
    }
}

// ---------------------------------------------------------------------------
// V4 (fused): each block walks the composed chunk maps from bestws down to
// its own chunk, then backtracks its chunk and writes the path slice.
// ---------------------------------------------------------------------------
__global__ __launch_bounds__(64) void bt_fill(
    const unsigned int* __restrict__ bpin, const int* __restrict__ Hin,
    const int* __restrict__ bestws, float* __restrict__ dout)
{
    __shared__ int Hl[CHUNKS*NT];
    __shared__ unsigned char bp[CLEN*NT];
    __shared__ float ob[CLEN];
    const int c = blockIdx.x, tid = threadIdx.x;
    for (int idx=tid; idx<CHUNKS*NT; idx+=64) Hl[idx] = Hin[idx];
    for (int idx=tid; idx<CLEN*NT/4; idx+=64)
        ((unsigned int*)bp)[idx] = bpin[(size_t)c*(CLEN*NT/4) + idx];
    __syncthreads();
    if (tid==0){
        int e = bestws[0];
        for (int cc=CHUNKS-1; cc>c; --cc) e = Hl[cc*NT+e];
        for (int t=CLEN-1;t>=0;--t){ ob[t] = (float)e; e = bp[t*NT+e]; }
    }
    __syncthreads();
    for (int idx=tid; idx<CLEN; idx+=64)
        dout[1 + c*CLEN + idx] = ob[idx];
}

// ---------------------------------------------------------------------------
extern "C" void kernel_launch(void* const* d_in, const int* in_sizes, int n_in,
                              void* d_out, int out_size, void* d_ws, size_t ws_size,
                              hipStream_t stream)
{
    const float* x    = (const float*)d_in[0];
    const float* wf   = (const float*)d_in[1];
    const float* bihf = (const float*)d_in[3];
    const float* bhhf = (const float*)d_in[4];
    const float* wb   = (const float*)d_in[5];
    const float* bihb = (const float*)d_in[7];
    const float* bhhb = (const float*)d_in[8];
    const float* wtag = (const float*)d_in[9];
    const float* btag = (const float*)d_in[10];
    const float* trans= (const float*)d_in[11];
    float* out = (float*)d_out;

    char* w = (char*)d_ws;
    ushort_t* Ah = (ushort_t*)w;         w += 25165824;   // 16384*768*2
    ushort_t* Al = (ushort_t*)w;         w += 25165824;
    ushort_t* Bh = (ushort_t*)w;         w += 2359296;    // 1536*768*2
    ushort_t* Bl = (ushort_t*)w;         w += 2359296;
    float* featsp = (float*)w;           w += 5242880;    // 4 * 16384*20 * 4B
    float* Pall  = (float*)w;            w += 204800;     // 128*400*4
    float* fvst  = (float*)w;            w += 10240;      // 128*20*4
    int* Hmap    = (int*)w;              w += 10240;      // 128*20*4
    unsigned int* bp = (unsigned int*)w; w += 327680;     // 16384*20 bytes
    int* best    = (int*)w;

    conv_kernel<<<13440, 256, 0, stream>>>(x, wf, wb, Ah, Al, Bh, Bl);
    gemm_fused<<<1024, 256, 0, stream>>>(Ah, Al, Bh, Bl, bihf, bhhf, bihb, bhhb,
                                         wtag, featsp);
    vit_chunkmat<<<CHUNKS, 512, 0, stream>>>(featsp, btag, trans, Pall);
    vit_scan<<<1, 128, 0, stream>>>(Pall, trans, fvst, out, best);
    vit_replay<<<CHUNKS, 64, 0, stream>>>(featsp, btag, trans, fvst, bp, Hmap);
    bt_fill<<<CHUNKS, 64, 0, stream>>>(bp, Hmap, best, out);
}